// Round 6
// baseline (161.478 us; speedup 1.0000x reference)
//
#include <hip/hip_runtime.h>
#include <math.h>

// Problem constants
#define BATCH 64
#define SEQL  512
#define DIN   256
#define NF    256
#define KS    3
#define KF    (KS * NF)        // 768

// Combined-channel formulation:
//   Xcat[b,lp,ch] (lp = l+1, rows 0 and 513 zero):
//     ch<256 -> bf16(x[b,l,ch]) ; ch>=256 -> Y[b,l,ch-256] = (x@U)*sigmoid(z)
//   out[b,l,f] = relu( sum_c Xc_flat[(b*XL+l)*XCH + c] * WcT[f][c] + bias[f] )
//   (c = k*512+ch — im2col is a flat sliding window over Xc rows)
#define XCH 512
#define XL  (SEQL + 2)
#define KC  (KS * XCH)          // 1536
#define BK  128                 // K-chunk: 4 MFMA sub-steps of 32
#define LDR 128                 // LDS row stride in shorts (256 B = 16x16B units)

typedef __attribute__((ext_vector_type(8))) short short8;
typedef __attribute__((ext_vector_type(4))) float floatx4;
typedef __attribute__((ext_vector_type(8))) unsigned short ushort8v;

static __device__ __forceinline__ unsigned short f2bf(float f) {
    unsigned int u = __float_as_uint(f);
    return (unsigned short)((u + 0x7FFF + ((u >> 16) & 1)) >> 16);  // RTNE
}

// async 16B/lane global->LDS; LDS dst = wave-uniform base + lane*16
static __device__ __forceinline__ void gl_lds16(const void* g, void* l) {
    __builtin_amdgcn_global_load_lds(
        (const __attribute__((address_space(1))) unsigned int*)g,
        (__attribute__((address_space(3))) unsigned int*)l, 16, 0, 0);
}

// Stage an nrows x 128-short tile (global row stride rs shorts) into LDS.
// LDS layout: [row][128] shorts, 16B units XOR-swizzled: u_dst = u_src^(row&15).
// nrows must be a multiple of 64 (so per-wave slab is a multiple of 16).
template <int NROWS>
static __device__ __forceinline__ void stage_tile(
    const unsigned short* __restrict__ gbase, size_t rs,
    unsigned short* lds, int wave, int lane)
{
    constexpr int WROWS = NROWS / 4;       // rows per wave (mult of 16)
    const int rsub = lane >> 4;            // 0..3 row within call
    const int ud   = lane & 15;            // dst 16B unit
    unsigned short* ldsw = lds + (size_t)(wave * WROWS) * LDR;
    const unsigned short* g = gbase + (size_t)(wave * WROWS) * rs;
    #pragma unroll
    for (int c = 0; c < WROWS / 4; ++c) {
        const int r  = c * 4 + rsub;       // local row (wave slab mult of 16)
        const int ug = ud ^ (r & 15);
        gl_lds16(g + (size_t)r * rs + ug * 8, ldsw + (size_t)(c * 4) * LDR);
    }
}

// ---------------------------------------------------------------------------
// pack: WcT[f][c] transpose (96 blk), UT[e][d] transpose (16 blk),
//       zero Xc pad rows (64 blk). 176 blocks x 256 threads.
// ---------------------------------------------------------------------------
__global__ __launch_bounds__(256) void pack_kernel(
    const float* __restrict__ U, const float* __restrict__ V,
    const float* __restrict__ Bw,
    unsigned short* __restrict__ WcT, unsigned short* __restrict__ UT,
    unsigned short* __restrict__ Xc)
{
    const int blk = blockIdx.x;
    const int t   = threadIdx.x;
    __shared__ unsigned short tile[64][64 + 2];

    if (blk < 96) {
        const int f0 = (blk & 3) * 64, c0 = (blk >> 2) * 64;
        const int fl = t & 63, cb = t >> 6;
        #pragma unroll
        for (int it = 0; it < 16; ++it) {
            const int cl = cb + it * 4;
            const int c  = c0 + cl;
            const int k  = c >> 9, ch = c & (XCH - 1);
            const float v = (ch < DIN) ? Bw[(size_t)ch * KF + k * NF + f0 + fl]
                                       : V[(size_t)(ch - DIN) * KF + k * NF + f0 + fl];
            tile[cl][fl] = f2bf(v);
        }
        __syncthreads();
        const int cl2 = t & 63, fb = t >> 6;
        #pragma unroll
        for (int it = 0; it < 16; ++it) {
            const int fl2 = fb + it * 4;
            WcT[(size_t)(f0 + fl2) * KC + c0 + cl2] = tile[cl2][fl2];
        }
    } else if (blk < 112) {
        const int bb = blk - 96;
        const int e0 = (bb & 3) * 64, d0 = (bb >> 2) * 64;
        const int el = t & 63, db = t >> 6;
        #pragma unroll
        for (int it = 0; it < 16; ++it) {
            const int dl = db + it * 4;
            tile[dl][el] = f2bf(U[(size_t)(d0 + dl) * DIN + e0 + el]);
        }
        __syncthreads();
        const int dl2 = t & 63, eb = t >> 6;
        #pragma unroll
        for (int it = 0; it < 16; ++it) {
            const int el2 = eb + it * 4;
            UT[(size_t)(e0 + el2) * DIN + d0 + dl2] = tile[dl2][el2];
        }
    } else {
        const int b = blk - 112;
        unsigned int* r0 = (unsigned int*)(Xc + (size_t)b * XL * XCH);
        unsigned int* r1 = (unsigned int*)(Xc + ((size_t)b * XL + XL - 1) * XCH);
        r0[t] = 0u;
        r1[t] = 0u;
    }
}

// ---------------------------------------------------------------------------
// stage1: Y = (x@U)*sigmoid(z) -> Xc Y-half; ft==0 blocks also write bf16
// x-half. M128 x N64 tile, BK=128 (2 chunks). Grid 1024 x 256, 3 blocks/CU.
// Wave w owns m-rows [w*32, w*32+32), all 64 n. acc[2][4].
// ---------------------------------------------------------------------------
__global__ __launch_bounds__(256, 3) void stage1_kernel(
    const float* __restrict__ x, const unsigned short* __restrict__ UT,
    const float* __restrict__ z, unsigned short* __restrict__ Xc)
{
    __shared__ unsigned short As[128 * LDR];   // 32 KB
    __shared__ unsigned short Bs[64 * LDR];    // 16 KB

    const int tid  = threadIdx.x;
    const int lane = tid & 63;
    const int wave = tid >> 6;
    const int quad = lane >> 4, l16 = lane & 15;

    const int bid   = blockIdx.x;
    const int ft    = bid & 3;                 // 4 e-tiles share A (adjacent)
    const int mt    = bid >> 2;
    const int b     = mt >> 2;
    const int lbase = (mt & 3) * 128;
    const int e0    = ft * 64;
    const bool writeX = (ft == 0);

    floatx4 acc[2][4] = {};

    for (int k0 = 0; k0 < DIN; k0 += BK) {
        // B tile: UT rows e0..e0+63, cols k0..k0+127
        stage_tile<64>(UT + (size_t)e0 * DIN + k0, DIN, Bs, wave, lane);

        // A tile: fp32 x -> bf16, swizzled LDS store (+ Xc x-half when ft==0)
        #pragma unroll
        for (int it = 0; it < 8; ++it) {
            const int idx = tid + it * 256;     // 0..2047 16B units
            const int row = idx >> 4;
            const int ud  = idx & 15;
            const int ug  = ud ^ (row & 15);
            const float* xp =
                x + ((size_t)b * SEQL + lbase + row) * DIN + k0 + ug * 8;
            const float4 v0 = *(const float4*)xp;
            const float4 v1 = *(const float4*)(xp + 4);
            ushort8v h;
            h[0] = f2bf(v0.x); h[1] = f2bf(v0.y); h[2] = f2bf(v0.z); h[3] = f2bf(v0.w);
            h[4] = f2bf(v1.x); h[5] = f2bf(v1.y); h[6] = f2bf(v1.z); h[7] = f2bf(v1.w);
            *(ushort8v*)&As[row * LDR + ud * 8] = h;
            if (writeX)
                *(ushort8v*)&Xc[((size_t)b * XL + lbase + 1 + row) * XCH + k0 + ug * 8] = h;
        }
        __syncthreads();

        #pragma unroll
        for (int ks = 0; ks < 4; ++ks) {        // four K=32 sub-steps
            short8 af[2], bfr[4];
            #pragma unroll
            for (int i = 0; i < 2; ++i) {
                const int m = wave * 32 + i * 16 + l16;
                af[i] = *(const short8*)&As[m * LDR + (((ks * 4 + quad) ^ l16) * 8)];
            }
            #pragma unroll
            for (int j = 0; j < 4; ++j) {
                const int n = j * 16 + l16;
                bfr[j] = *(const short8*)&Bs[n * LDR + (((ks * 4 + quad) ^ l16) * 8)];
            }
            #pragma unroll
            for (int i = 0; i < 2; ++i)
                #pragma unroll
                for (int j = 0; j < 4; ++j)
                    acc[i][j] = __builtin_amdgcn_mfma_f32_16x16x32_bf16(
                        af[i], bfr[j], acc[i][j], 0, 0, 0);
        }
        __syncthreads();
    }

    // epilogue: scale by sigmoid(z[b,e]), bf16 into Y-half (lp = l+1)
    #pragma unroll
    for (int j = 0; j < 4; ++j) {
        const int e = e0 + j * 16 + l16;
        const float zf = 1.0f / (1.0f + expf(-z[(size_t)b * DIN + e]));
        #pragma unroll
        for (int i = 0; i < 2; ++i) {
            const int lrow = lbase + wave * 32 + i * 16 + quad * 4;
            #pragma unroll
            for (int r = 0; r < 4; ++r)
                Xc[((size_t)b * XL + lrow + r + 1) * XCH + DIN + e] =
                    f2bf(acc[i][j][r] * zf);
        }
    }
}

// ---------------------------------------------------------------------------
// stage2: out = relu(A @ WcT^T + bias), A = flat sliding window over Xc.
// M128 x N64 tile, BK=128, K=1536. Chunk order tap-grouped (ch-group outer,
// tap inner) so the 3 taps' overlapping A rows hit L2. Grid 1024 x 256,
// 48 KB LDS -> 3 blocks/CU.
// ---------------------------------------------------------------------------
__global__ __launch_bounds__(256, 3) void stage2_kernel(
    const unsigned short* __restrict__ Xc,
    const unsigned short* __restrict__ WcT,
    const float* __restrict__ bias, float* __restrict__ out)
{
    __shared__ unsigned short As[128 * LDR];   // 32 KB
    __shared__ unsigned short Bs[64 * LDR];    // 16 KB

    const int tid  = threadIdx.x;
    const int lane = tid & 63;
    const int wave = tid >> 6;
    const int quad = lane >> 4, l16 = lane & 15;

    const int bid   = blockIdx.x;
    const int ft    = bid & 3;                 // 4 f-tiles share A (adjacent)
    const int mt    = bid >> 2;
    const int b     = mt >> 2;
    const int lbase = (mt & 3) * 128;
    const int f0    = ft * 64;

    const unsigned short* gA = Xc + ((size_t)b * XL + lbase) * XCH;  // flat window
    const unsigned short* gB = WcT + (size_t)f0 * KC;

    floatx4 acc[2][4] = {};

    #pragma unroll 1
    for (int g = 0; g < 4; ++g) {              // ch-group (128 channels)
        #pragma unroll 1
        for (int k = 0; k < KS; ++k) {         // tap (A rows shift by k)
            const int c0 = k * XCH + g * 128;
            stage_tile<128>(gA + c0, XCH, As, wave, lane);
            stage_tile<64>(gB + c0, KC, Bs, wave, lane);
            __syncthreads();

            #pragma unroll
            for (int ks = 0; ks < 4; ++ks) {
                short8 af[2], bfr[4];
                #pragma unroll
                for (int i = 0; i < 2; ++i) {
                    const int m = wave * 32 + i * 16 + l16;
                    af[i] = *(const short8*)&As[m * LDR + (((ks * 4 + quad) ^ l16) * 8)];
                }
                #pragma unroll
                for (int j = 0; j < 4; ++j) {
                    const int n = j * 16 + l16;
                    bfr[j] = *(const short8*)&Bs[n * LDR + (((ks * 4 + quad) ^ l16) * 8)];
                }
                #pragma unroll
                for (int i = 0; i < 2; ++i)
                    #pragma unroll
                    for (int j = 0; j < 4; ++j)
                        acc[i][j] = __builtin_amdgcn_mfma_f32_16x16x32_bf16(
                            af[i], bfr[j], acc[i][j], 0, 0, 0);
            }
            __syncthreads();
        }
    }

    #pragma unroll
    for (int j = 0; j < 4; ++j) {
        const int f  = f0 + j * 16 + l16;
        const float bv = bias[f];
        #pragma unroll
        for (int i = 0; i < 2; ++i) {
            const int lrow = lbase + wave * 32 + i * 16 + quad * 4;
            #pragma unroll
            for (int r = 0; r < 4; ++r) {
                const float v = acc[i][j][r] + bv;
                out[((size_t)b * SEQL + lrow + r) * NF + f] = fmaxf(v, 0.0f);
            }
        }
    }
}

extern "C" void kernel_launch(void* const* d_in, const int* in_sizes, int n_in,
                              void* d_out, int out_size, void* d_ws, size_t ws_size,
                              hipStream_t stream) {
    const float* x    = (const float*)d_in[0];
    const float* z    = (const float*)d_in[1];
    const float* U    = (const float*)d_in[2];
    const float* V    = (const float*)d_in[3];
    const float* Bw   = (const float*)d_in[4];
    const float* bias = (const float*)d_in[5];

    unsigned short* Xc  = (unsigned short*)d_ws;          // 64*514*512*2 B
    unsigned short* WcT = Xc + (size_t)BATCH * XL * XCH;  // 256*1536*2 B
    unsigned short* UT  = WcT + (size_t)NF * KC;          // 256*256*2 B
    float* out = (float*)d_out;

    pack_kernel<<<dim3(176), 256, 0, stream>>>(U, V, Bw, WcT, UT, Xc);
    stage1_kernel<<<dim3(1024), 256, 0, stream>>>(x, UT, z, Xc);
    stage2_kernel<<<dim3(1024), 256, 0, stream>>>(Xc, WcT, bias, out);
}

// Round 7
// 139.788 us; speedup vs baseline: 1.1552x; 1.1552x over previous
//
#include <hip/hip_runtime.h>
#include <math.h>

// Problem constants
#define BATCH 64
#define SEQL  512
#define DIN   256
#define NF    256
#define KS    3
#define KF    (KS * NF)        // 768

// Combined-channel formulation:
//   Xcat[b,lp,ch] (lp = l+1, rows 0 and 513 zero):
//     ch<256 -> bf16(x[b,l,ch]) ; ch>=256 -> Y[b,l,ch-256] = (x@U)*sigmoid(z)
//   out[b,l,f] = relu( sum_{k,ch} Xc[b][l+k][ch] * WcT[f][k*512+ch] + bias[f] )
#define XCH 512
#define XL  (SEQL + 2)
#define KC  (KS * XCH)          // 1536
#define LDR 128                 // stage2 LDS row stride in shorts (256 B)
#define AROWS 136               // stage2 A tile rows (128 + 2 halo, padded to stage granularity)

typedef __attribute__((ext_vector_type(8))) short short8;
typedef __attribute__((ext_vector_type(4))) float floatx4;
typedef __attribute__((ext_vector_type(8))) unsigned short ushort8v;

static __device__ __forceinline__ unsigned short f2bf(float f) {
    unsigned int u = __float_as_uint(f);
    return (unsigned short)((u + 0x7FFF + ((u >> 16) & 1)) >> 16);  // RTNE
}

// async 16B/lane global->LDS; LDS dst = wave-uniform base + lane*16
static __device__ __forceinline__ void gl_lds16(const void* g, void* l) {
    __builtin_amdgcn_global_load_lds(
        (const __attribute__((address_space(1))) unsigned int*)g,
        (__attribute__((address_space(3))) unsigned int*)l, 16, 0, 0);
}

// Stage NROWS x 128-short tile (global row stride rs) into LDS, 256B rows,
// 16B units XOR-swizzled u_dst = u_src ^ (row&15). NROWS multiple of 16.
template <int NROWS>
static __device__ __forceinline__ void stage_tile(
    const unsigned short* __restrict__ gbase, size_t rs,
    unsigned short* lds, int wave, int lane)
{
    constexpr int WROWS = NROWS / 4;       // rows per wave (multiple of 16)
    const int rsub = lane >> 4;            // 0..3
    const int ud   = lane & 15;
    unsigned short* ldsw = lds + (size_t)(wave * WROWS) * LDR;
    const unsigned short* g = gbase + (size_t)(wave * WROWS) * rs;
    #pragma unroll
    for (int c = 0; c < WROWS / 4; ++c) {
        const int r  = c * 4 + rsub;       // wave slab mult of 16 -> (r&15) ok
        const int ug = ud ^ (r & 15);
        gl_lds16(g + (size_t)r * rs + ug * 8, ldsw + (size_t)(c * 4) * LDR);
    }
}

// ---------------------------------------------------------------------------
// pack: WcT[f][c] transpose (96 blk), UT[e][d] transpose (16 blk),
//       zero Xc pad rows (64 blk). 176 blocks x 256 threads.
// ---------------------------------------------------------------------------
__global__ __launch_bounds__(256) void pack_kernel(
    const float* __restrict__ U, const float* __restrict__ V,
    const float* __restrict__ Bw,
    unsigned short* __restrict__ WcT, unsigned short* __restrict__ UT,
    unsigned short* __restrict__ Xc)
{
    const int blk = blockIdx.x;
    const int t   = threadIdx.x;
    __shared__ unsigned short tile[64][64 + 2];

    if (blk < 96) {
        const int f0 = (blk & 3) * 64, c0 = (blk >> 2) * 64;
        const int fl = t & 63, cb = t >> 6;
        #pragma unroll
        for (int it = 0; it < 16; ++it) {
            const int cl = cb + it * 4;
            const int c  = c0 + cl;
            const int k  = c >> 9, ch = c & (XCH - 1);
            const float v = (ch < DIN) ? Bw[(size_t)ch * KF + k * NF + f0 + fl]
                                       : V[(size_t)(ch - DIN) * KF + k * NF + f0 + fl];
            tile[cl][fl] = f2bf(v);
        }
        __syncthreads();
        const int cl2 = t & 63, fb = t >> 6;
        #pragma unroll
        for (int it = 0; it < 16; ++it) {
            const int fl2 = fb + it * 4;
            WcT[(size_t)(f0 + fl2) * KC + c0 + cl2] = tile[cl2][fl2];
        }
    } else if (blk < 112) {
        const int bb = blk - 96;
        const int e0 = (bb & 3) * 64, d0 = (bb >> 2) * 64;
        const int el = t & 63, db = t >> 6;
        #pragma unroll
        for (int it = 0; it < 16; ++it) {
            const int dl = db + it * 4;
            tile[dl][el] = f2bf(U[(size_t)(d0 + dl) * DIN + e0 + el]);
        }
        __syncthreads();
        const int dl2 = t & 63, eb = t >> 6;
        #pragma unroll
        for (int it = 0; it < 16; ++it) {
            const int el2 = eb + it * 4;
            UT[(size_t)(e0 + el2) * DIN + d0 + dl2] = tile[dl2][el2];
        }
    } else {
        const int b = blk - 112;
        unsigned int* r0 = (unsigned int*)(Xc + (size_t)b * XL * XCH);
        unsigned int* r1 = (unsigned int*)(Xc + ((size_t)b * XL + XL - 1) * XCH);
        r0[t] = 0u;
        r1[t] = 0u;
    }
}

// ---------------------------------------------------------------------------
// stage1: Y = (x@U)*sigmoid(z) -> Xc Y-half; ft==0 also writes bf16 x-half.
// M64 x N128 tile, BK=64, K=256. Grid 1024 x 256 (~4 blocks/CU).
// LDS rows 128 B (64 shorts), 8-unit XOR swizzle. Vectorized epilogue via LDS.
// bid layout: ft = (bid>>3)&1, mt = (bid>>4)*8 + (bid&7)  (XCD-friendly).
// ---------------------------------------------------------------------------
__global__ __launch_bounds__(256, 4) void stage1_kernel(
    const float* __restrict__ x, const unsigned short* __restrict__ UT,
    const float* __restrict__ z, unsigned short* __restrict__ Xc)
{
    __shared__ unsigned short sh[16384];   // 32 KB: As 64x64 | Bs 128x64
    unsigned short* As = sh;               // [64][64]
    unsigned short* Bs = sh + 4096;        // [128][64]

    const int tid  = threadIdx.x;
    const int lane = tid & 63;
    const int wave = tid >> 6;
    const int quad = lane >> 4, l16 = lane & 15;

    const int bid   = blockIdx.x;
    const int ft    = (bid >> 3) & 1;
    const int mt    = ((bid >> 4) << 3) | (bid & 7);   // 0..511
    const int b     = mt >> 3;
    const int lbase = (mt & 7) * 64;
    const int e0    = ft * 128;
    const bool writeX = (ft == 0);

    const int r8  = lane >> 3;     // 0..7
    const int ud8 = lane & 7;

    floatx4 acc[4][2] = {};

    for (int k0 = 0; k0 < DIN; k0 += 64) {
        // B tile: UT rows e0..e0+127, cols k0..k0+63 (32 rows/wave, 4 calls)
        #pragma unroll
        for (int c = 0; c < 4; ++c) {
            const int r  = wave * 32 + c * 8 + r8;
            const int ug = ud8 ^ (r & 7);
            gl_lds16(UT + (size_t)(e0 + r) * DIN + k0 + ug * 8,
                     Bs + (size_t)(wave * 32 + c * 8) * 64);
        }
        // A tile: fp32 x -> bf16 (+ Xc x-half when ft==0). 512 units, 2/thread.
        #pragma unroll
        for (int it = 0; it < 2; ++it) {
            const int idx = tid + it * 256;     // 0..511
            const int row = idx >> 3;
            const int u   = idx & 7;
            const int ug  = u ^ (row & 7);
            const float* xp =
                x + ((size_t)b * SEQL + lbase + row) * DIN + k0 + ug * 8;
            const float4 v0 = *(const float4*)xp;
            const float4 v1 = *(const float4*)(xp + 4);
            ushort8v h;
            h[0] = f2bf(v0.x); h[1] = f2bf(v0.y); h[2] = f2bf(v0.z); h[3] = f2bf(v0.w);
            h[4] = f2bf(v1.x); h[5] = f2bf(v1.y); h[6] = f2bf(v1.z); h[7] = f2bf(v1.w);
            *(ushort8v*)&As[row * 64 + u * 8] = h;
            if (writeX)
                *(ushort8v*)&Xc[((size_t)b * XL + lbase + 1 + row) * XCH + k0 + ug * 8] = h;
        }
        __syncthreads();

        #pragma unroll
        for (int ks = 0; ks < 2; ++ks) {
            short8 af[4], bfr[2];
            #pragma unroll
            for (int i = 0; i < 4; ++i) {
                const int m = i * 16 + l16;
                af[i] = *(const short8*)&As[m * 64 + (((ks * 4 + quad) ^ (l16 & 7)) * 8)];
            }
            #pragma unroll
            for (int j = 0; j < 2; ++j) {
                const int n = wave * 32 + j * 16 + l16;
                bfr[j] = *(const short8*)&Bs[n * 64 + (((ks * 4 + quad) ^ (l16 & 7)) * 8)];
            }
            #pragma unroll
            for (int i = 0; i < 4; ++i)
                #pragma unroll
                for (int j = 0; j < 2; ++j)
                    acc[i][j] = __builtin_amdgcn_mfma_f32_16x16x32_bf16(
                        af[i], bfr[j], acc[i][j], 0, 0, 0);
        }
        __syncthreads();
    }

    // epilogue: scale by sigmoid, transpose through LDS (sh = [64][128] bf16),
    // then 16B vectorized stores to the Xc Y-half.
    #pragma unroll
    for (int j = 0; j < 2; ++j) {
        const int el = wave * 32 + j * 16 + l16;          // 0..127
        const float zf = 1.0f / (1.0f + expf(-z[(size_t)b * DIN + e0 + el]));
        #pragma unroll
        for (int i = 0; i < 4; ++i) {
            const int m = i * 16 + quad * 4;
            #pragma unroll
            for (int r = 0; r < 4; ++r)
                sh[(m + r) * 128 + el] = f2bf(acc[i][j][r] * zf);
        }
    }
    __syncthreads();
    #pragma unroll
    for (int it = 0; it < 4; ++it) {
        const int idx = tid + it * 256;                   // 0..1023
        const int row = idx >> 4;
        const int u   = idx & 15;
        *(ushort8v*)&Xc[((size_t)b * XL + lbase + 1 + row) * XCH + DIN + e0 + u * 8] =
            *(const ushort8v*)&sh[row * 128 + u * 8];
    }
}

// ---------------------------------------------------------------------------
// stage2: out = relu(conv(Xc) + bias). M128 x N64, K = 4 ch-groups x 3 taps
// x 128ch. A-halo tile (136 rows) staged ONCE per ch-group; taps read LDS
// with +k row shift. Grid 1024 x 256, LDS 50.8 KB -> 3 blocks/CU.
// bid layout: ft = (bid>>3)&3, mt = (bid>>5)*8 + (bid&7) — the 4 ft blocks
// sharing an A-slab are == mod 8 (same XCD) and dispatch-adjacent.
// ---------------------------------------------------------------------------
__global__ __launch_bounds__(256, 3) void stage2_kernel(
    const unsigned short* __restrict__ Xc,
    const unsigned short* __restrict__ WcT,
    const float* __restrict__ bias, float* __restrict__ out)
{
    __shared__ unsigned short As[AROWS * LDR];   // 34.8 KB
    __shared__ unsigned short Bs[64 * LDR];      // 16 KB

    const int tid  = threadIdx.x;
    const int lane = tid & 63;
    const int wave = tid >> 6;
    const int quad = lane >> 4, l16 = lane & 15;

    const int bid   = blockIdx.x;
    const int ft    = (bid >> 3) & 3;
    const int mt    = ((bid >> 5) << 3) | (bid & 7);   // 0..255
    const int b     = mt >> 2;
    const int lbase = (mt & 3) * 128;
    const int f0    = ft * 64;

    const unsigned short* gA = Xc + ((size_t)b * XL + lbase) * XCH;
    const unsigned short* gB = WcT + (size_t)f0 * KC;

    // A-halo staging distribution: 136 rows = 34 4-row calls over 4 waves
    const int rsub = lane >> 4;
    const int ud   = lane & 15;
    const int wr0   = (wave < 2) ? wave * 36 : 72 + (wave - 2) * 32;
    const int ncall = (wave < 2) ? 9 : 8;

    floatx4 acc[2][4] = {};

    #pragma unroll 1
    for (int g = 0; g < 4; ++g) {                 // 128-channel group
        // stage A rows lbase..lbase+135, cols g*128..+127 (once per group)
        #pragma unroll
        for (int c = 0; c < 9; ++c) {
            if (c < ncall) {
                const int r  = wr0 + c * 4 + rsub;
                const int ug = ud ^ (r & 15);
                gl_lds16(gA + (size_t)r * XCH + g * 128 + ug * 8,
                         As + (size_t)(wr0 + c * 4) * LDR);
            }
        }
        #pragma unroll 1
        for (int k = 0; k < KS; ++k) {            // tap: LDS row shift by k
            stage_tile<64>(gB + k * XCH + g * 128, KC, Bs, wave, lane);
            __syncthreads();

            #pragma unroll
            for (int ks = 0; ks < 4; ++ks) {
                short8 af[2], bfr[4];
                #pragma unroll
                for (int i = 0; i < 2; ++i) {
                    const int m = wave * 32 + i * 16 + l16;
                    af[i] = *(const short8*)
                        &As[(m + k) * LDR + (((ks * 4 + quad) ^ ((l16 + k) & 15)) * 8)];
                }
                #pragma unroll
                for (int j = 0; j < 4; ++j) {
                    const int n = j * 16 + l16;
                    bfr[j] = *(const short8*)
                        &Bs[n * LDR + (((ks * 4 + quad) ^ l16) * 8)];
                }
                #pragma unroll
                for (int i = 0; i < 2; ++i)
                    #pragma unroll
                    for (int j = 0; j < 4; ++j)
                        acc[i][j] = __builtin_amdgcn_mfma_f32_16x16x32_bf16(
                            af[i], bfr[j], acc[i][j], 0, 0, 0);
            }
            __syncthreads();
        }
    }

    #pragma unroll
    for (int j = 0; j < 4; ++j) {
        const int f  = f0 + j * 16 + l16;
        const float bv = bias[f];
        #pragma unroll
        for (int i = 0; i < 2; ++i) {
            const int lrow = lbase + wave * 32 + i * 16 + quad * 4;
            #pragma unroll
            for (int r = 0; r < 4; ++r) {
                const float v = acc[i][j][r] + bv;
                out[((size_t)b * SEQL + lrow + r) * NF + f] = fmaxf(v, 0.0f);
            }
        }
    }
}

extern "C" void kernel_launch(void* const* d_in, const int* in_sizes, int n_in,
                              void* d_out, int out_size, void* d_ws, size_t ws_size,
                              hipStream_t stream) {
    const float* x    = (const float*)d_in[0];
    const float* z    = (const float*)d_in[1];
    const float* U    = (const float*)d_in[2];
    const float* V    = (const float*)d_in[3];
    const float* Bw   = (const float*)d_in[4];
    const float* bias = (const float*)d_in[5];

    unsigned short* Xc  = (unsigned short*)d_ws;          // 64*514*512*2 B
    unsigned short* WcT = Xc + (size_t)BATCH * XL * XCH;  // 256*1536*2 B
    unsigned short* UT  = WcT + (size_t)NF * KC;          // 256*256*2 B
    float* out = (float*)d_out;

    pack_kernel<<<dim3(176), 256, 0, stream>>>(U, V, Bw, WcT, UT, Xc);
    stage1_kernel<<<dim3(1024), 256, 0, stream>>>(x, UT, z, Xc);
    stage2_kernel<<<dim3(1024), 256, 0, stream>>>(Xc, WcT, bias, out);
}